// Round 15
// baseline (134.602 us; speedup 1.0000x reference)
//
#include <hip/hip_runtime.h>

#define HIDDEN 768
#define HEADS 12
#define HEAD_DIM 64
#define DEPTH 8
#define BB 4
#define SS 512
#define MM (BB * SS)           // 2048
#define NQD (HIDDEN * DEPTH)   // 6144

typedef __bf16 bf16x8 __attribute__((ext_vector_type(8)));
typedef float f32x4 __attribute__((ext_vector_type(4)));
typedef float f32x16 __attribute__((ext_vector_type(16)));
typedef unsigned short u16x8 __attribute__((ext_vector_type(8)));

static __device__ __forceinline__ unsigned short f2bf(float f) {
  union { float f; unsigned u; } c; c.f = f;
  unsigned u = c.u;
  u = u + 0x7fffu + ((u >> 16) & 1u);   // RNE
  return (unsigned short)(u >> 16);
}

static __device__ __forceinline__ unsigned cvt_pk_bf16(float lo, float hi) {
  unsigned r;
  asm("v_cvt_pk_bf16_f32 %0, %1, %2" : "=v"(r) : "v"(lo), "v"(hi));
  return r;
}

static __device__ __forceinline__ void gld16(const void* g, void* l) {
  __builtin_amdgcn_global_load_lds((const __attribute__((address_space(1))) void*)g,
                                   (__attribute__((address_space(3))) void*)l, 16, 0, 0);
}

// ---------------------------------------------------------------- ONE merged convert kernel
// chunks of 8 f32 -> 8 bf16 (32B read, 16B write). Segments: hs | Wv | Wqd-perm | Wkd-perm.
// Last block handles the bias permute.
#define CH_A  (MM * HIDDEN / 8)        // 196608
#define CH_WV (HIDDEN * HIDDEN / 8)    // 73728
#define CH_W  (NQD * HIDDEN / 8)       // 589824
#define CH_TOTAL (CH_A + CH_WV + 2 * CH_W)   // 1449984 = 5664 * 256

__global__ __launch_bounds__(256) void convert_all(
    const float* __restrict__ hs, const float* __restrict__ Wv,
    const float* __restrict__ Wqd, const float* __restrict__ Wkd,
    const float* __restrict__ bqd, const float* __restrict__ bkd,
    unsigned short* __restrict__ A_bf, unsigned short* __restrict__ Wv_bf,
    unsigned short* __restrict__ Wqk_bf, float* __restrict__ bqk_p) {
  const int tid = threadIdx.x;
  if (blockIdx.x == gridDim.x - 1) {      // bias permute block
    for (int j = tid; j < NQD; j += 256) {
      int nr = (j & ~511) | ((j & 7) << 6) | ((j >> 3) & 63);
      bqk_p[nr] = bqd[j];
      bqk_p[NQD + nr] = bkd[j];
    }
    return;
  }
  int i = blockIdx.x * 256 + tid;
  const float* src;
  unsigned short* dst;
  if (i < CH_A) {
    src = hs + (size_t)i * 8;
    dst = A_bf + (size_t)i * 8;
  } else if (i < CH_A + CH_WV) {
    int j = i - CH_A;
    src = Wv + (size_t)j * 8;
    dst = Wv_bf + (size_t)j * 8;
  } else {
    int j = i - CH_A - CH_WV;
    const float* w = Wqd;
    unsigned short* dW = Wqk_bf;
    if (j >= CH_W) { j -= CH_W; w = Wkd; dW += (size_t)NQD * HIDDEN; }
    int row = j / 96;                    // 96 chunks per 768-wide row
    int cg  = j - row * 96;
    int nr = (row & ~511) | ((row & 7) << 6) | ((row >> 3) & 63);
    src = w + (size_t)j * 8;
    dst = dW + (size_t)nr * HIDDEN + cg * 8;
  }
  f32x4 lo = *reinterpret_cast<const f32x4*>(src);
  f32x4 hi = *reinterpret_cast<const f32x4*>(src + 4);
  union { unsigned u[4]; u16x8 v; } r;
  r.u[0] = cvt_pk_bf16(lo.x, lo.y);
  r.u[1] = cvt_pk_bf16(lo.z, lo.w);
  r.u[2] = cvt_pk_bf16(hi.x, hi.y);
  r.u[3] = cvt_pk_bf16(hi.z, hi.w);
  *reinterpret_cast<u16x8*>(dst) = r.v;
}

// ---------------------------------------------------------------- small GEMM (Vt): unchanged 128x128 structure
__global__ __launch_bounds__(256) void gemm_bt(
    const unsigned short* __restrict__ A, const unsigned short* __restrict__ W,
    const float* __restrict__ bias, unsigned short* __restrict__ out0, int K) {
  __shared__ unsigned short At[2][4096];
  __shared__ unsigned short Bt[2][4096];
  const int tid = threadIdx.x;
  const int nwg = gridDim.x * gridDim.y;
  const int orig = blockIdx.y * gridDim.x + blockIdx.x;
  const int wg = (orig & 7) * (nwg >> 3) + (orig >> 3);
  const int bm = (wg % gridDim.x) * 128;
  const int bn = (wg / gridDim.x) * 128;
  const int wave = tid >> 6, lane = tid & 63;
  const int wm = (wave >> 1) * 64, wn = (wave & 1) * 64;
  const int lg = lane >> 4, lr = lane & 15;
  const int srow = tid >> 2, scol = (tid & 3) * 8;
  f32x4 acc[4][4] = {};
  const unsigned short* aptr = A + (size_t)(bm + srow) * K + scol;
  const unsigned short* wptr = W + (size_t)(bn + srow) * K + scol;

  auto stage = [&](int buf, int k0) {
    gld16(aptr + k0,                  &At[buf][tid * 8]);
    gld16(aptr + (size_t)64 * K + k0, &At[buf][2048 + tid * 8]);
    gld16(wptr + k0,                  &Bt[buf][tid * 8]);
    gld16(wptr + (size_t)64 * K + k0, &Bt[buf][2048 + tid * 8]);
  };

  stage(0, 0);
  __syncthreads();

  int cur = 0;
  for (int k0 = 32; k0 <= K; k0 += 32) {
    if (k0 < K) stage(cur ^ 1, k0);
    bf16x8 af[4], bfr[4];
#pragma unroll
    for (int mi = 0; mi < 4; ++mi)
      af[mi] = *reinterpret_cast<const bf16x8*>(&At[cur][(wm + mi * 16 + lr) * 32 + lg * 8]);
#pragma unroll
    for (int ni = 0; ni < 4; ++ni)
      bfr[ni] = *reinterpret_cast<const bf16x8*>(&Bt[cur][(wn + ni * 16 + lr) * 32 + lg * 8]);
#pragma unroll
    for (int mi = 0; mi < 4; ++mi)
#pragma unroll
      for (int ni = 0; ni < 4; ++ni)
        acc[mi][ni] = __builtin_amdgcn_mfma_f32_16x16x32_bf16(af[mi], bfr[ni], acc[mi][ni], 0, 0, 0);
    __syncthreads();
    cur ^= 1;
  }

#pragma unroll
  for (int mi = 0; mi < 4; ++mi)
#pragma unroll
    for (int ni = 0; ni < 4; ++ni)
#pragma unroll
      for (int i = 0; i < 4; ++i) {
        int m = bm + wm + mi * 16 + lg * 4 + i;   // Wv row (n_v)
        int n = bn + wn + ni * 16 + lr;           // X row (b*512+s)
        float v = acc[mi][ni][i] + bias[m];
        size_t addr = ((size_t)((n >> 9) * 12 + (m >> 6)) * 64 + (size_t)(m & 63)) * 512 + (size_t)(n & 511);
        out0[addr] = f2bf(v);
      }
}

// ---------------------------------------------------------------- big GEMM (Qd|Kd): 256x192 tile, 512 blocks (2/CU),
// 8 waves, BK=32, DEPTH-2 reg-staged pipeline (named sets A/B), one barrier/phase.
// W is pre-permuted bf16 (convert_all). LDS swizzle byte^=((row>>1)&3)<<4 on write.
__global__ __launch_bounds__(512, 2) void gemm_qk256(
    const unsigned short* __restrict__ A, const unsigned short* __restrict__ W,
    const float* __restrict__ bias, unsigned short* __restrict__ out0,
    unsigned short* __restrict__ out1, int K) {
  __shared__ unsigned short At[2][8192];   // 256 x 32 (swizzled content)
  __shared__ unsigned short Bt[2][6144];   // 192 x 32 (swizzled content)
  const int tid = threadIdx.x;
  const int nwg = gridDim.x * gridDim.y;   // 512
  const int orig = blockIdx.y * gridDim.x + blockIdx.x;
  const int wg = (orig & 7) * (nwg >> 3) + (orig >> 3);
  const int bm = (wg % gridDim.x) * 256;
  const int bn = (wg / gridDim.x) * 192;
  const int wave = tid >> 6, lane = tid & 63;
  const int wr = wave >> 2, wc = wave & 3;          // 2(M) x 4(N)
  const int lg = lane >> 4, lr = lane & 15;

  // staging granule map: thread -> (row, col-elem); swizzled LDS byte offsets
  const int rA0 = tid >> 2,           cA0 = (tid & 3) << 3;
  const int rA1 = (tid + 512) >> 2;                          // rows 128..255
  const bool hasB1 = tid < 256;
  const int rB1 = (tid + 512) >> 2;                          // rows 128..191 (tid<256)
  const int dA0 = rA0 * 64 + ((cA0 << 1) ^ (((rA0 >> 1) & 3) << 4));
  const int dA1 = rA1 * 64 + ((cA0 << 1) ^ (((rA1 >> 1) & 3) << 4));
  const int dB0 = dA0;
  const int dB1 = rB1 * 64 + ((cA0 << 1) ^ (((rB1 >> 1) & 3) << 4));
  const unsigned short* pA0 = A + (size_t)(bm + rA0) * K + cA0;
  const unsigned short* pA1 = A + (size_t)(bm + rA1) * K + cA0;
  const unsigned short* pB0 = W + (size_t)(bn + rA0) * K + cA0;
  const unsigned short* pB1 = W + (size_t)(bn + rB1) * K + cA0;

  // two NAMED register staging sets (rule #20: no runtime-indexed reg arrays)
  u16x8 a0A = {}, a1A = {}, b0A = {}, b1A = {};
  u16x8 a0B = {}, a1B = {}, b0B = {}, b1B = {};

  auto gloadA = [&](int k0) {
    a0A = *reinterpret_cast<const u16x8*>(pA0 + k0);
    a1A = *reinterpret_cast<const u16x8*>(pA1 + k0);
    b0A = *reinterpret_cast<const u16x8*>(pB0 + k0);
    if (hasB1) b1A = *reinterpret_cast<const u16x8*>(pB1 + k0);
  };
  auto gloadB = [&](int k0) {
    a0B = *reinterpret_cast<const u16x8*>(pA0 + k0);
    a1B = *reinterpret_cast<const u16x8*>(pA1 + k0);
    b0B = *reinterpret_cast<const u16x8*>(pB0 + k0);
    if (hasB1) b1B = *reinterpret_cast<const u16x8*>(pB1 + k0);
  };
  auto lwriteA = [&](int buf) {
    *reinterpret_cast<u16x8*>((char*)At[buf] + dA0) = a0A;
    *reinterpret_cast<u16x8*>((char*)At[buf] + dA1) = a1A;
    *reinterpret_cast<u16x8*>((char*)Bt[buf] + dB0) = b0A;
    if (hasB1) *reinterpret_cast<u16x8*>((char*)Bt[buf] + dB1) = b1A;
  };
  auto lwriteB = [&](int buf) {
    *reinterpret_cast<u16x8*>((char*)At[buf] + dA0) = a0B;
    *reinterpret_cast<u16x8*>((char*)At[buf] + dA1) = a1B;
    *reinterpret_cast<u16x8*>((char*)Bt[buf] + dB0) = b0B;
    if (hasB1) *reinterpret_cast<u16x8*>((char*)Bt[buf] + dB1) = b1B;
  };

  // read-side swizzle depends only on lr (row bases are multiples of 16)
  const int rdswz = ((((lr >> 1) & 3) ^ lg) << 4);   // byte offset within 64B row

  f32x4 acc[8][3] = {};
  auto compute = [&](int buf) {
    bf16x8 af[8], bfr[3];
    const char* abase = (const char*)At[buf];
    const char* bbase = (const char*)Bt[buf];
#pragma unroll
    for (int mi = 0; mi < 8; ++mi) {
      const int row = wr * 128 + mi * 16 + lr;
      af[mi] = *reinterpret_cast<const bf16x8*>(abase + row * 64 + rdswz);
    }
#pragma unroll
    for (int ni = 0; ni < 3; ++ni) {
      const int row = wc * 48 + ni * 16 + lr;
      bfr[ni] = *reinterpret_cast<const bf16x8*>(bbase + row * 64 + rdswz);
    }
#pragma unroll
    for (int mi = 0; mi < 8; ++mi)
#pragma unroll
      for (int ni = 0; ni < 3; ++ni)
        acc[mi][ni] = __builtin_amdgcn_mfma_f32_16x16x32_bf16(af[mi], bfr[ni], acc[mi][ni], 0, 0, 0);
  };

  const int NT = K / 32;                 // 24 (even)
  gloadA(0);
  gloadB(32);
  lwriteA(0);
  __syncthreads();

  for (int tt = 0; tt < NT; tt += 2) {
    if (tt + 2 < NT) gloadA((tt + 2) * 32);
    compute(0);
    if (tt + 1 < NT) lwriteB(1);
    __syncthreads();
    if (tt + 1 < NT) {
      if (tt + 3 < NT) gloadB((tt + 3) * 32);
      compute(1);
      if (tt + 2 < NT) lwriteA(0);
      __syncthreads();
    }
  }

  unsigned short* outp = out0;
  int nbase = 0;
  float scale = 0.125f;                 // Qd pre-scaled by 1/8
  if (bn >= NQD) { outp = out1; nbase = NQD; scale = 1.0f; }
#pragma unroll
  for (int mi = 0; mi < 8; ++mi)
#pragma unroll
    for (int ni = 0; ni < 3; ++ni)
#pragma unroll
      for (int i = 0; i < 4; ++i) {
        int m = bm + wr * 128 + mi * 16 + lg * 4 + i;
        int n = bn + wc * 48 + ni * 16 + lr;
        float v = (acc[mi][ni][i] + bias[n]) * scale;
        int nr = n - nbase;
        size_t addr = ((size_t)(((m >> 9) * 12 + (nr >> 9)) * 8 + ((nr >> 6) & 7)) * 512 + (size_t)(m & 511)) * 64 + (size_t)(nr & 63);
        outp[addr] = f2bf(v);
      }
}

// ---------------------------------------------------------------- fused attention, 32x32 swapped structure (+ T5 setprio)
__global__ __launch_bounds__(256) void attn32(
    const unsigned short* __restrict__ Qd, const unsigned short* __restrict__ Kd,
    const unsigned short* __restrict__ Vt, const int* __restrict__ mask,
    float* __restrict__ out) {
  __shared__ unsigned char KsB[64 * 128];   // [k][e] bf16, byte^((row&7)<<4) swizzle
  __shared__ unsigned char VsB[64 * 128];   // [e][k] bf16, same swizzle
  __shared__ float mLds[64];
  __shared__ int mflag;
  const int tid = threadIdx.x;
  const int bid = blockIdx.x;
  const int qt = bid & 3;
  const int inst = bid >> 2;         // (b*12+h)*8 + d
  const int bh = inst >> 3;
  const int b = bh / 12;
  const int wave = tid >> 6, lane = tid & 63;
  const int l31 = lane & 31, hi = lane >> 5;
  const size_t qkbase = (size_t)inst * (SS * 64);
  const size_t vbase = (size_t)bh * (64 * SS);

  if (tid == 0) mflag = 0;
  __syncthreads();
  {
    int m0 = mask[b * SS + tid], m1 = mask[b * SS + 256 + tid];
    if ((m0 == 0) || (m1 == 0)) mflag = 1;
  }
  __syncthreads();
  const bool hasmask = (mflag != 0);

  const int q0w = qt * 128 + wave * 32;
  bf16x8 aq[4];
  {
    const unsigned short* qrow = Qd + qkbase + (size_t)(q0w + l31) * 64 + 8 * hi;
#pragma unroll
    for (int s = 0; s < 4; ++s)
      aq[s] = *reinterpret_cast<const bf16x8*>(qrow + 16 * s);
  }

  const int sr = tid >> 3;
  const int sc = (tid & 7) * 8;
  const int swz_lo = sr * 128 + ((sc * 2) ^ ((sr & 7) << 4));
  const int swz_hi = (sr + 32) * 128 + ((sc * 2) ^ (((sr + 32) & 7) << 4));

  f32x16 o[2] = {};
  float psum = 0.f;

  u16x8 rk0 = *reinterpret_cast<const u16x8*>(&Kd[qkbase + (size_t)sr * 64 + sc]);
  u16x8 rk1 = *reinterpret_cast<const u16x8*>(&Kd[qkbase + (size_t)(sr + 32) * 64 + sc]);
  u16x8 rv0 = *reinterpret_cast<const u16x8*>(&Vt[vbase + (size_t)sr * SS + sc]);
  u16x8 rv1 = *reinterpret_cast<const u16x8*>(&Vt[vbase + (size_t)(sr + 32) * SS + sc]);

  for (int t = 0; t < SS / 64; ++t) {
    *reinterpret_cast<u16x8*>(KsB + swz_lo) = rk0;
    *reinterpret_cast<u16x8*>(KsB + swz_hi) = rk1;
    *reinterpret_cast<u16x8*>(VsB + swz_lo) = rv0;
    *reinterpret_cast<u16x8*>(VsB + swz_hi) = rv1;
    if (hasmask && tid < 64) mLds[tid] = mask[b * SS + t * 64 + tid] ? 0.f : -1e9f;
    __syncthreads();

    if (t < SS / 64 - 1) {
      const int kn = (t + 1) * 64;
      rk0 = *reinterpret_cast<const u16x8*>(&Kd[qkbase + (size_t)(kn + sr) * 64 + sc]);
      rk1 = *reinterpret_cast<const u16x8*>(&Kd[qkbase + (size_t)(kn + sr + 32) * 64 + sc]);
      rv0 = *reinterpret_cast<const u16x8*>(&Vt[vbase + (size_t)sr * SS + kn + sc]);
      rv1 = *reinterpret_cast<const u16x8*>(&Vt[vbase + (size_t)(sr + 32) * SS + kn + sc]);
    }

    f32x16 st[2];
    __builtin_amdgcn_s_setprio(1);
#pragma unroll
    for (int kh = 0; kh < 2; ++kh) {
      f32x16 acc = {};
      const int row = kh * 32 + l31;
      const int rswz = (row & 7) << 4;
#pragma unroll
      for (int s = 0; s < 4; ++s) {
        bf16x8 ak = *reinterpret_cast<const bf16x8*>(KsB + row * 128 + ((32 * s + 16 * hi) ^ rswz));
        acc = __builtin_amdgcn_mfma_f32_32x32x16_bf16(ak, aq[s], acc, 0, 0, 0);
      }
      st[kh] = acc;
    }
    __builtin_amdgcn_s_setprio(0);

    if (hasmask) {
#pragma unroll
      for (int h = 0; h < 2; ++h)
#pragma unroll
        for (int r = 0; r < 16; ++r)
          st[h][r] += mLds[32 * h + (r & 3) + 8 * (r >> 2) + 4 * hi];
    }

    float pv[2][16];
#pragma unroll
    for (int h = 0; h < 2; ++h)
#pragma unroll
      for (int r = 0; r < 16; ++r) {
        float p = __expf(st[h][r]);
        psum += p;
        pv[h][r] = p;
      }

    __builtin_amdgcn_s_setprio(1);
#pragma unroll
    for (int ks = 0; ks < 4; ++ks) {
      const int h = ks >> 1, rb = 8 * (ks & 1);
      unsigned w0 = cvt_pk_bf16(pv[h][rb + 0], pv[h][rb + 1]);
      unsigned w1 = cvt_pk_bf16(pv[h][rb + 2], pv[h][rb + 3]);
      unsigned w2 = cvt_pk_bf16(pv[h][rb + 4], pv[h][rb + 5]);
      unsigned w3 = cvt_pk_bf16(pv[h][rb + 6], pv[h][rb + 7]);
      asm("v_permlane32_swap_b32 %0, %1" : "+v"(w0), "+v"(w2));
      asm("v_permlane32_swap_b32 %0, %1" : "+v"(w1), "+v"(w3));
      union { unsigned u[4]; bf16x8 v; } pa;
      pa.u[0] = w0; pa.u[1] = w1; pa.u[2] = w2; pa.u[3] = w3;
#pragma unroll
      for (int et = 0; et < 2; ++et) {
        const int vrow = 32 * et + l31;
        bf16x8 bv = *reinterpret_cast<const bf16x8*>(
            VsB + vrow * 128 + ((32 * ks + 16 * hi) ^ ((vrow & 7) << 4)));
        o[et] = __builtin_amdgcn_mfma_f32_32x32x16_bf16(pa.v, bv, o[et], 0, 0, 0);
      }
    }
    __builtin_amdgcn_s_setprio(0);
    __syncthreads();
  }

  psum += __shfl_xor(psum, 32);
  float inv = 1.f / psum;
  float iv[16];
#pragma unroll
  for (int r = 0; r < 16; ++r)
    iv[r] = __shfl(inv, (r & 3) + 8 * (r >> 2) + 4 * hi);

  const int d = inst & 7;
  const int hh = bh % 12;
  const size_t obase = (((size_t)d * BB + b) * HEADS + hh) * (SS * 64);
#pragma unroll
  for (int et = 0; et < 2; ++et)
#pragma unroll
    for (int r = 0; r < 16; ++r) {
      const int qrow = (r & 3) + 8 * (r >> 2) + 4 * hi;
      out[obase + (size_t)(q0w + qrow) * 64 + 32 * et + l31] = o[et][r] * iv[r];
    }
}

// ----------------------------------------------------------------
extern "C" void kernel_launch(void* const* d_in, const int* in_sizes, int n_in,
                              void* d_out, int out_size, void* d_ws, size_t ws_size,
                              hipStream_t stream) {
  const float* hs  = (const float*)d_in[0];
  const int* mask  = (const int*)d_in[1];
  const float* Wv  = (const float*)d_in[6];
  const float* bv  = (const float*)d_in[7];
  const float* Wqd = (const float*)d_in[8];
  const float* bqd = (const float*)d_in[9];
  const float* Wkd = (const float*)d_in[10];
  const float* bkd = (const float*)d_in[11];

  char* ws = (char*)d_ws;
  unsigned short* A_bf   = (unsigned short*)ws; ws += (size_t)MM * HIDDEN * 2;
  unsigned short* Wv_bf  = (unsigned short*)ws; ws += (size_t)HIDDEN * HIDDEN * 2;
  unsigned short* Wqk_bf = (unsigned short*)ws; ws += (size_t)(2 * NQD) * HIDDEN * 2; // Wqd|Wkd permuted
  float*          bqk_p  = (float*)ws;          ws += (size_t)(2 * NQD) * 4;          // permuted biases
  unsigned short* Qd     = (unsigned short*)ws; ws += (size_t)MM * NQD * 2;
  unsigned short* Kd     = (unsigned short*)ws; ws += (size_t)MM * NQD * 2;
  unsigned short* Vt     = (unsigned short*)ws; ws += (size_t)MM * HIDDEN * 2;

  convert_all<<<CH_TOTAL / 256 + 1, 256, 0, stream>>>(
      hs, Wv, Wqd, Wkd, bqd, bkd, A_bf, Wv_bf, Wqk_bf, bqk_p);

  // V^T gemm: A=Wv (M=768), W=X (N=2048) -> Vt[bh][e][s]
  gemm_bt<<<dim3(HIDDEN / 128, MM / 128), 256, 0, stream>>>(
      Wv_bf, A_bf, bv, Vt, HIDDEN);
  // merged Qd|Kd gemm: A=X (M=2048), W=Wqk (N=12288), 256x192 tile, 512 blocks
  gemm_qk256<<<dim3(MM / 256, 2 * NQD / 192), 512, 0, stream>>>(
      A_bf, Wqk_bf, bqk_p, Qd, Kd, HIDDEN);

  attn32<<<BB * HEADS * DEPTH * (SS / 128), 256, 0, stream>>>(Qd, Kd, Vt, mask, (float*)d_out);
}